// Round 2
// baseline (737.222 us; speedup 1.0000x reference)
//
#include <hip/hip_runtime.h>

#define NN 64
#define TT 64
#define MM 2
#define VV 25
#define CI 64
#define CO 128
#define EMBH 64

// ws layout (float offsets)
#define WS_EJW 0         // 25*128 = 3200
#define WS_EF  3200      // 64*128 = 8192
#define WS_S   11392     // 128
#define WS_BC  11520     // 128
#define WS_CT  11648     // 64*128 = 8192
#define WS_WT  19840     // 128*3*128 = 49152  (wt[c][k][o] = tcn_w[o][c][k])
#define WS_H   68992     // 64*64*2*25*128 = 26214400
#define XOUT_ELEMS 26214400

// ---------------- k0a: ej MLP -> ejW fold, plus BN fold ----------------
__global__ void k0a_ej(const float* __restrict__ ej_w1, const float* __restrict__ ej_b1,
                       const float* __restrict__ ej_w2, const float* __restrict__ ej_b2,
                       const float* __restrict__ gcn_w, const float* __restrict__ tcn_b,
                       const float* __restrict__ bn_gamma, const float* __restrict__ bn_beta,
                       const float* __restrict__ bn_mean, const float* __restrict__ bn_var,
                       float* __restrict__ ws) {
  __shared__ float tmp1[VV * EMBH];  // relu(ej_w1+b1)
  __shared__ float ejs[VV * EMBH];   // ej rows
  int tid = threadIdx.x;
  for (int i = tid; i < VV * EMBH; i += 256)
    tmp1[i] = fmaxf(ej_w1[i] + ej_b1[i & 63], 0.f);
  __syncthreads();
  for (int i = tid; i < VV * EMBH; i += 256) {
    int v = i >> 6, c = i & 63;
    float a = ej_b2[c];
    for (int h = 0; h < EMBH; ++h) a += tmp1[v * EMBH + h] * ej_w2[h * CI + c];
    ejs[i] = fmaxf(a, 0.f);
  }
  __syncthreads();
  // ejW[v][o] = sum_c ej[v][c] * gcn_w[(64+c)*128 + o]
  for (int i = tid; i < VV * CO; i += 256) {
    int v = i >> 7, o = i & 127;
    float a = 0.f;
    for (int c = 0; c < CI; ++c) a += ejs[v * EMBH + c] * gcn_w[(CI + c) * CO + o];
    ws[WS_EJW + i] = a;
  }
  if (tid < CO) {
    float s = bn_gamma[tid] * rsqrtf(bn_var[tid] + 1e-5f);
    ws[WS_S + tid] = s;
    ws[WS_BC + tid] = tcn_b[tid] * s + bn_beta[tid] - bn_mean[tid] * s;
  }
}

// ---------------- k0b: ef[t][o], one block per t ----------------
__global__ void k0b_ef(const float* __restrict__ ef_w1, const float* __restrict__ ef_b1,
                       const float* __restrict__ ef_w2, const float* __restrict__ ef_b2,
                       float* __restrict__ ws) {
  __shared__ float tf[EMBH];
  int t = blockIdx.x, o = threadIdx.x;
  if (o < EMBH) tf[o] = fmaxf(ef_w1[t * EMBH + o] + ef_b1[o], 0.f);
  __syncthreads();
  float a = ef_b2[o];
#pragma unroll
  for (int h = 0; h < EMBH; ++h) a += tf[h] * ef_w2[h * CO + o];
  ws[WS_EF + t * CO + o] = fmaxf(a, 0.f);
}

// ---------------- k_wt: wt[(c*3+k)*128+o] = tcn_w[o*384 + c*3 + k] ----------------
__global__ void k_wt(const float* __restrict__ tcn_w, float* __restrict__ wt) {
  int j = blockIdx.x * 256 + threadIdx.x;
  if (j >= CO * 3 * CO) return;
  int o = j & 127, r = j >> 7, k = r % 3, c = r / 3;
  wt[j] = tcn_w[o * (CO * 3) + c * 3 + k];
}

// ---------------- k1_ct: ct[t][o] = conv(ef)[o,t]*s[o] + bc[o] ----------------
__global__ void k1_ct(const float* __restrict__ ws_ro, float* __restrict__ ct_out) {
  __shared__ float ef3[3 * CO];
  int t = blockIdx.x, o = threadIdx.x;
  for (int i = o; i < 3 * CO; i += 128) {
    int k = i >> 7, c = i & 127, tt = t + k - 1;
    ef3[i] = (tt >= 0 && tt < TT) ? ws_ro[WS_EF + tt * CO + c] : 0.f;
  }
  __syncthreads();
  const float* wt = ws_ro + WS_WT;
  float a = 0.f;
  for (int c = 0; c < CO; ++c) {
    a += ef3[c] * wt[(c * 3 + 0) * CO + o]
       + ef3[CO + c] * wt[(c * 3 + 1) * CO + o]
       + ef3[2 * CO + c] * wt[(c * 3 + 2) * CO + o];
  }
  ct_out[t * CO + o] = a * ws_ro[WS_S + o] + ws_ro[WS_BC + o];
}

// ---------------- GCN: h = relu(G @ (x@Wtop + ejW) + b), per (n,t,m) ----------------
__global__ void __launch_bounds__(256) k_gcn(const float* __restrict__ x, const float* __restrict__ G,
                                             const float* __restrict__ gcn_w, const float* __restrict__ gcn_b,
                                             const float* __restrict__ ejW, float* __restrict__ h_ws) {
  __shared__ float xs[VV * CI];   // 1600
  __shared__ float Gs[VV * VV];   // 625
  __shared__ float Ps[VV * CO];   // 3200
  int ntm = blockIdx.x;
  int tid = threadIdx.x;
  const float* xb = x + (size_t)ntm * (VV * CI);
  for (int i = tid; i < VV * CI; i += 256) xs[i] = xb[i];
  const float* Gb = G + (size_t)ntm * (VV * VV);
  for (int i = tid; i < VV * VV; i += 256) Gs[i] = Gb[i];
  __syncthreads();
  int o = tid & 127, half = tid >> 7;
  float wreg[CI];
#pragma unroll
  for (int c = 0; c < CI; ++c) wreg[c] = gcn_w[c * CO + o];
  for (int v = half; v < VV; v += 2) {
    float a = ejW[v * CO + o];
    const float4* xv = (const float4*)&xs[v * CI];
#pragma unroll
    for (int c4 = 0; c4 < CI / 4; ++c4) {
      float4 q = xv[c4];
      a += q.x * wreg[4 * c4] + q.y * wreg[4 * c4 + 1] + q.z * wreg[4 * c4 + 2] + q.w * wreg[4 * c4 + 3];
    }
    Ps[v * CO + o] = a;
  }
  __syncthreads();
  float bo = gcn_b[o];
  float* hb = h_ws + (size_t)ntm * (VV * CO);
  for (int u = half; u < VV; u += 2) {
    float a = bo;
#pragma unroll
    for (int v = 0; v < VV; ++v) a += Gs[u * VV + v] * Ps[v * CO + o];
    hb[u * CO + o] = fmaxf(a, 0.f);
  }
}

// ---------------- TCN: y = relu(conv1d(h)*s + ct), per (n,m,v) ----------------
__global__ void __launch_bounds__(256) k_tcn(const float* __restrict__ ws_ro,
                                             float* __restrict__ out) {
  __shared__ float hs[CO][68];  // transposed [c][t+1], rows 16B aligned
  int b = blockIdx.x;
  int n = b / (MM * VV), r = b % (MM * VV), m = r / VV, v = r % VV;
  int tid = threadIdx.x;
  const float* hbase = ws_ro + WS_H + ((size_t)((n * TT) * MM + m) * VV + v) * CO;
  for (int i = tid; i < TT * CO; i += 256) {
    int t = i >> 7, c = i & 127;
    hs[c][t + 1] = hbase[(size_t)t * (MM * VV * CO) + c];
  }
  if (tid < CO) { hs[tid][0] = 0.f; hs[tid][65] = 0.f; hs[tid][66] = 0.f; hs[tid][67] = 0.f; }
  __syncthreads();
  int o = tid & 127, th = tid >> 7, t0 = th << 5;
  float acc[32];
#pragma unroll
  for (int t = 0; t < 32; ++t) acc[t] = 0.f;
  const float* wi = ws_ro + WS_WT + o;  // lane-coalesced weight stream
  for (int c = 0; c < CO; ++c) {
    float w0 = wi[(c * 3 + 0) * CO];
    float w1 = wi[(c * 3 + 1) * CO];
    float w2 = wi[(c * 3 + 2) * CO];
    float hh[36];
    float4* hq = (float4*)hh;
    const float4* hp = (const float4*)&hs[c][t0];
#pragma unroll
    for (int q = 0; q < 9; ++q) hq[q] = hp[q];
#pragma unroll
    for (int t = 0; t < 32; ++t)
      acc[t] += hh[t] * w0 + hh[t + 1] * w1 + hh[t + 2] * w2;
  }
  float so = ws_ro[WS_S + o];
  float* ob = out + ((size_t)((n * TT) * MM + m) * VV + v) * CO;
#pragma unroll
  for (int t = 0; t < 32; ++t) {
    int gt = t0 + t;
    ob[(size_t)gt * (MM * VV * CO) + o] = fmaxf(acc[t] * so + ws_ro[WS_CT + gt * CO + o], 0.f);
  }
}

// ---------------- ADJ: g_out[n,t,m,u,o] = adj_b[o] + sum_{i,k} G[n,t+k-1,m,u,i]*adj_w[o,i,k] ----------------
__global__ void k_adj(const float* __restrict__ G, const float* __restrict__ adj_w,
                      const float* __restrict__ adj_b, float* __restrict__ gout) {
  __shared__ float Gs3[3 * VV * VV];  // [k][u][i]
  __shared__ float wls[VV * VV * 3];  // [o][i][k]
  int ntm = blockIdx.x;
  int n = ntm / (TT * MM), r = ntm % (TT * MM), t = r / MM, m = r % MM;
  int tid = threadIdx.x;
  for (int i = tid; i < 3 * VV * VV; i += 256) {
    int k = i / (VV * VV), e = i % (VV * VV), tt = t + k - 1;
    Gs3[i] = (tt >= 0 && tt < TT) ? G[((size_t)((n * TT + tt) * MM + m)) * (VV * VV) + e] : 0.f;
  }
  for (int i = tid; i < VV * VV * 3; i += 256) wls[i] = adj_w[i];
  __syncthreads();
  for (int e = tid; e < VV * VV; e += 256) {
    int u = e / VV, o = e % VV;
    float a = adj_b[o];
#pragma unroll
    for (int i = 0; i < VV; ++i) {
      a += Gs3[u * VV + i] * wls[o * 75 + i * 3]
         + Gs3[VV * VV + u * VV + i] * wls[o * 75 + i * 3 + 1]
         + Gs3[2 * VV * VV + u * VV + i] * wls[o * 75 + i * 3 + 2];
    }
    gout[(size_t)ntm * (VV * VV) + e] = a;
  }
}

extern "C" void kernel_launch(void* const* d_in, const int* in_sizes, int n_in,
                              void* d_out, int out_size, void* d_ws, size_t ws_size,
                              hipStream_t stream) {
  const float* x     = (const float*)d_in[0];
  const float* G     = (const float*)d_in[1];
  const float* ej_w1 = (const float*)d_in[2];
  const float* ej_b1 = (const float*)d_in[3];
  const float* ej_w2 = (const float*)d_in[4];
  const float* ej_b2 = (const float*)d_in[5];
  const float* ef_w1 = (const float*)d_in[6];
  const float* ef_b1 = (const float*)d_in[7];
  const float* ef_w2 = (const float*)d_in[8];
  const float* ef_b2 = (const float*)d_in[9];
  const float* gcn_w = (const float*)d_in[10];
  const float* gcn_b = (const float*)d_in[11];
  const float* tcn_w = (const float*)d_in[12];
  const float* tcn_b = (const float*)d_in[13];
  const float* bn_g  = (const float*)d_in[14];
  const float* bn_b  = (const float*)d_in[15];
  const float* bn_m  = (const float*)d_in[16];
  const float* bn_v  = (const float*)d_in[17];
  const float* adj_w = (const float*)d_in[18];
  const float* adj_b = (const float*)d_in[19];
  float* out = (float*)d_out;
  float* ws  = (float*)d_ws;

  k0a_ej<<<1, 256, 0, stream>>>(ej_w1, ej_b1, ej_w2, ej_b2, gcn_w, tcn_b, bn_g, bn_b, bn_m, bn_v, ws);
  k0b_ef<<<TT, CO, 0, stream>>>(ef_w1, ef_b1, ef_w2, ef_b2, ws);
  k_wt<<<(CO * 3 * CO + 255) / 256, 256, 0, stream>>>(tcn_w, ws + WS_WT);
  k1_ct<<<TT, CO, 0, stream>>>(ws, ws + WS_CT);
  k_gcn<<<NN * TT * MM, 256, 0, stream>>>(x, G, gcn_w, gcn_b, ws + WS_EJW, ws + WS_H);
  k_tcn<<<NN * MM * VV, 256, 0, stream>>>(ws, out);
  k_adj<<<NN * TT * MM, 256, 0, stream>>>(G, adj_w, adj_b, out + XOUT_ELEMS);
}

// Round 5
// 726.514 us; speedup vs baseline: 1.0147x; 1.0147x over previous
//
#include <hip/hip_runtime.h>

#define NN 64
#define TT 64
#define MM 2
#define VV 25
#define CI 64
#define CO 128
#define EMBH 64

// ws layout (float offsets)
#define WS_EJW 0         // 25*128 = 3200
#define WS_EF  3200      // 64*128 = 8192
#define WS_S   11392     // 128
#define WS_BC  11520     // 128
#define WS_CT  11648     // 64*128 = 8192
#define WS_WT4 19840     // 128*128*4 (+512 slack) = 66048  (wt4[c][o][k], k padded to 4)
#define WS_H   85888     // 64*64*2*25*128 = 26214400
#define XOUT_ELEMS 26214400

// ---------------- k0a: ej MLP -> ejW fold, plus BN fold ----------------
__global__ void k0a_ej(const float* __restrict__ ej_w1, const float* __restrict__ ej_b1,
                       const float* __restrict__ ej_w2, const float* __restrict__ ej_b2,
                       const float* __restrict__ gcn_w, const float* __restrict__ tcn_b,
                       const float* __restrict__ bn_gamma, const float* __restrict__ bn_beta,
                       const float* __restrict__ bn_mean, const float* __restrict__ bn_var,
                       float* __restrict__ ws) {
  __shared__ float tmp1[VV * EMBH];  // relu(ej_w1+b1)
  __shared__ float ejs[VV * EMBH];   // ej rows
  int tid = threadIdx.x;
  for (int i = tid; i < VV * EMBH; i += 256)
    tmp1[i] = fmaxf(ej_w1[i] + ej_b1[i & 63], 0.f);
  __syncthreads();
  for (int i = tid; i < VV * EMBH; i += 256) {
    int v = i >> 6, c = i & 63;
    float a = ej_b2[c];
    for (int h = 0; h < EMBH; ++h) a += tmp1[v * EMBH + h] * ej_w2[h * CI + c];
    ejs[i] = fmaxf(a, 0.f);
  }
  __syncthreads();
  // ejW[v][o] = sum_c ej[v][c] * gcn_w[(64+c)*128 + o]
  for (int i = tid; i < VV * CO; i += 256) {
    int v = i >> 7, o = i & 127;
    float a = 0.f;
    for (int c = 0; c < CI; ++c) a += ejs[v * EMBH + c] * gcn_w[(CI + c) * CO + o];
    ws[WS_EJW + i] = a;
  }
  if (tid < CO) {
    float s = bn_gamma[tid] * rsqrtf(bn_var[tid] + 1e-5f);
    ws[WS_S + tid] = s;
    ws[WS_BC + tid] = tcn_b[tid] * s + bn_beta[tid] - bn_mean[tid] * s;
  }
}

// ---------------- k0b: ef[t][o], one block per t ----------------
__global__ void k0b_ef(const float* __restrict__ ef_w1, const float* __restrict__ ef_b1,
                       const float* __restrict__ ef_w2, const float* __restrict__ ef_b2,
                       float* __restrict__ ws) {
  __shared__ float tf[EMBH];
  int t = blockIdx.x, o = threadIdx.x;
  if (o < EMBH) tf[o] = fmaxf(ef_w1[t * EMBH + o] + ef_b1[o], 0.f);
  __syncthreads();
  float a = ef_b2[o];
#pragma unroll
  for (int h = 0; h < EMBH; ++h) a += tf[h] * ef_w2[h * CO + o];
  ws[WS_EF + t * CO + o] = fmaxf(a, 0.f);
}

// ---------------- k_wt: wt4[(c*128+o)*4+k] = tcn_w[o*384 + c*3 + k] ----------------
__global__ void k_wt(const float* __restrict__ tcn_w, float* __restrict__ wt4) {
  int j = blockIdx.x * 256 + threadIdx.x;
  if (j >= CO * CO) return;
  int o = j & 127, c = j >> 7;
  float4 w;
  w.x = tcn_w[o * (CO * 3) + c * 3 + 0];
  w.y = tcn_w[o * (CO * 3) + c * 3 + 1];
  w.z = tcn_w[o * (CO * 3) + c * 3 + 2];
  w.w = 0.f;
  ((float4*)wt4)[j] = w;
}

// ---------------- k1_ct: ct[t][o] = conv(ef)[o,t]*s[o] + bc[o] ----------------
__global__ void k1_ct(const float* __restrict__ ws_ro, float* __restrict__ ct_out) {
  __shared__ float ef3[3 * CO];
  int t = blockIdx.x, o = threadIdx.x;
  for (int i = o; i < 3 * CO; i += 128) {
    int k = i >> 7, c = i & 127, tt = t + k - 1;
    ef3[i] = (tt >= 0 && tt < TT) ? ws_ro[WS_EF + tt * CO + c] : 0.f;
  }
  __syncthreads();
  const float4* w4 = (const float4*)(ws_ro + WS_WT4);
  float a = 0.f;
  for (int c = 0; c < CO; ++c) {
    float4 wq = w4[c * CO + o];
    a += ef3[c] * wq.x + ef3[CO + c] * wq.y + ef3[2 * CO + c] * wq.z;
  }
  ct_out[t * CO + o] = a * ws_ro[WS_S + o] + ws_ro[WS_BC + o];
}

// ---------------- GCN: h = relu(G @ (x@Wtop + ejW) + b), per (n,t,m) ----------------
__global__ void __launch_bounds__(256, 4) k_gcn(const float* __restrict__ x, const float* __restrict__ G,
                                                const float* __restrict__ gcn_w, const float* __restrict__ gcn_b,
                                                const float* __restrict__ ejW, float* __restrict__ h_ws) {
  __shared__ float xs[VV * CI];   // 1600
  __shared__ float Gs[VV * VV];   // 625
  __shared__ float Ps[VV * CO];   // 3200
  int ntm = blockIdx.x;
  int tid = threadIdx.x;
  const float* xb = x + (size_t)ntm * (VV * CI);
  for (int i = tid; i < VV * CI; i += 256) xs[i] = xb[i];
  const float* Gb = G + (size_t)ntm * (VV * VV);
  for (int i = tid; i < VV * VV; i += 256) Gs[i] = Gb[i];
  __syncthreads();
  int o = tid & 127, half = tid >> 7;
  float wreg[CI];
#pragma unroll
  for (int c = 0; c < CI; ++c) wreg[c] = gcn_w[c * CO + o];
  for (int v = half; v < VV; v += 2) {
    float a = ejW[v * CO + o];
    const float4* xv = (const float4*)&xs[v * CI];
#pragma unroll
    for (int c4 = 0; c4 < CI / 4; ++c4) {
      float4 q = xv[c4];
      a += q.x * wreg[4 * c4] + q.y * wreg[4 * c4 + 1] + q.z * wreg[4 * c4 + 2] + q.w * wreg[4 * c4 + 3];
    }
    Ps[v * CO + o] = a;
  }
  __syncthreads();
  float bo = gcn_b[o];
  float* hb = h_ws + (size_t)ntm * (VV * CO);
  for (int u = half; u < VV; u += 2) {
    float a = bo;
#pragma unroll
    for (int v = 0; v < VV; ++v) a += Gs[u * VV + v] * Ps[v * CO + o];
    hb[u * CO + o] = fmaxf(a, 0.f);
  }
}

// ---------------- TCN: y = relu(conv1d(h)*s + ct), per (n,m,v) ----------------
__global__ void __launch_bounds__(256, 4) k_tcn(const float* __restrict__ ws_ro,
                                                float* __restrict__ out) {
  __shared__ float hs[CO][68];  // transposed [c][t+1], rows 16B aligned (272 B)
  int b = blockIdx.x;
  int n = b / (MM * VV), r = b % (MM * VV), m = r / VV, v = r % VV;
  int tid = threadIdx.x;
  const float* hbase = ws_ro + WS_H + ((size_t)((n * TT) * MM + m) * VV + v) * CO;
  for (int i = tid; i < TT * CO; i += 256) {
    int t = i >> 7, c = i & 127;
    hs[c][t + 1] = hbase[(size_t)t * (MM * VV * CO) + c];
  }
  if (tid < CO) { hs[tid][0] = 0.f; hs[tid][65] = 0.f; hs[tid][66] = 0.f; hs[tid][67] = 0.f; }
  __syncthreads();
  int o = tid & 127, th = tid >> 7, t0 = th << 5;
  float acc[32];
#pragma unroll
  for (int t = 0; t < 32; ++t) acc[t] = 0.f;
  const float4* w4 = (const float4*)(ws_ro + WS_WT4) + o;  // stride CO between c's
  float4 w = w4[0];
  for (int c = 0; c < CO; ++c) {
    float4 wn = w;
    if (c < CO - 1) wn = w4[(c + 1) * CO];          // prefetch next c's weights
    const float4* hp = (const float4*)&hs[c][t0];   // wave-uniform address -> broadcast
    float4 q0 = hp[0], q1 = hp[1], q2 = hp[2], q3 = hp[3], q4 = hp[4],
           q5 = hp[5], q6 = hp[6], q7 = hp[7], q8 = hp[8];
    float w0 = w.x, w1 = w.y, w2 = w.z;
#define STEP(g, qa, qb)                                   \
    acc[4*g+0] += qa.x * w0 + qa.y * w1 + qa.z * w2;      \
    acc[4*g+1] += qa.y * w0 + qa.z * w1 + qa.w * w2;      \
    acc[4*g+2] += qa.z * w0 + qa.w * w1 + qb.x * w2;      \
    acc[4*g+3] += qa.w * w0 + qb.x * w1 + qb.y * w2;
    STEP(0, q0, q1) STEP(1, q1, q2) STEP(2, q2, q3) STEP(3, q3, q4)
    STEP(4, q4, q5) STEP(5, q5, q6) STEP(6, q6, q7) STEP(7, q7, q8)
#undef STEP
    w = wn;
  }
  float so = ws_ro[WS_S + o];
  float* ob = out + ((size_t)((n * TT) * MM + m) * VV + v) * CO;
#pragma unroll
  for (int t = 0; t < 32; ++t) {
    int gt = t0 + t;
    ob[(size_t)gt * (MM * VV * CO) + o] = fmaxf(acc[t] * so + ws_ro[WS_CT + gt * CO + o], 0.f);
  }
}

// ---------------- ADJ: g_out[n,t,m,u,o] = adj_b[o] + sum_{i,k} G[n,t+k-1,m,u,i]*adj_w[o,i,k] ----------------
__global__ void k_adj(const float* __restrict__ G, const float* __restrict__ adj_w,
                      const float* __restrict__ adj_b, float* __restrict__ gout) {
  __shared__ float Gs3[3 * VV * VV];  // [k][u][i]
  __shared__ float wls[VV * VV * 3];  // [o][i][k]
  int ntm = blockIdx.x;
  int n = ntm / (TT * MM), r = ntm % (TT * MM), t = r / MM, m = r % MM;
  int tid = threadIdx.x;
  for (int i = tid; i < 3 * VV * VV; i += 256) {
    int k = i / (VV * VV), e = i % (VV * VV), tt = t + k - 1;
    Gs3[i] = (tt >= 0 && tt < TT) ? G[((size_t)((n * TT + tt) * MM + m)) * (VV * VV) + e] : 0.f;
  }
  for (int i = tid; i < VV * VV * 3; i += 256) wls[i] = adj_w[i];
  __syncthreads();
  for (int e = tid; e < VV * VV; e += 256) {
    int u = e / VV, o = e % VV;
    float a = adj_b[o];
#pragma unroll
    for (int i = 0; i < VV; ++i) {
      a += Gs3[u * VV + i] * wls[o * 75 + i * 3]
         + Gs3[VV * VV + u * VV + i] * wls[o * 75 + i * 3 + 1]
         + Gs3[2 * VV * VV + u * VV + i] * wls[o * 75 + i * 3 + 2];
    }
    gout[(size_t)ntm * (VV * VV) + e] = a;
  }
}

extern "C" void kernel_launch(void* const* d_in, const int* in_sizes, int n_in,
                              void* d_out, int out_size, void* d_ws, size_t ws_size,
                              hipStream_t stream) {
  const float* x     = (const float*)d_in[0];
  const float* G     = (const float*)d_in[1];
  const float* ej_w1 = (const float*)d_in[2];
  const float* ej_b1 = (const float*)d_in[3];
  const float* ej_w2 = (const float*)d_in[4];
  const float* ej_b2 = (const float*)d_in[5];
  const float* ef_w1 = (const float*)d_in[6];
  const float* ef_b1 = (const float*)d_in[7];
  const float* ef_w2 = (const float*)d_in[8];
  const float* ef_b2 = (const float*)d_in[9];
  const float* gcn_w = (const float*)d_in[10];
  const float* gcn_b = (const float*)d_in[11];
  const float* tcn_w = (const float*)d_in[12];
  const float* tcn_b = (const float*)d_in[13];
  const float* bn_g  = (const float*)d_in[14];
  const float* bn_b  = (const float*)d_in[15];
  const float* bn_m  = (const float*)d_in[16];
  const float* bn_v  = (const float*)d_in[17];
  const float* adj_w = (const float*)d_in[18];
  const float* adj_b = (const float*)d_in[19];
  float* out = (float*)d_out;
  float* ws  = (float*)d_ws;

  k0a_ej<<<1, 256, 0, stream>>>(ej_w1, ej_b1, ej_w2, ej_b2, gcn_w, tcn_b, bn_g, bn_b, bn_m, bn_v, ws);
  k0b_ef<<<TT, CO, 0, stream>>>(ef_w1, ef_b1, ef_w2, ef_b2, ws);
  k_wt<<<(CO * CO + 255) / 256, 256, 0, stream>>>(tcn_w, ws + WS_WT4);
  k1_ct<<<TT, CO, 0, stream>>>(ws, ws + WS_CT);
  k_gcn<<<NN * TT * MM, 256, 0, stream>>>(x, G, gcn_w, gcn_b, ws + WS_EJW, ws + WS_H);
  k_tcn<<<NN * MM * VV, 256, 0, stream>>>(ws, out);
  k_adj<<<NN * TT * MM, 256, 0, stream>>>(G, adj_w, adj_b, out + XOUT_ELEMS);
}